// Round 6
// baseline (2305.192 us; speedup 1.0000x reference)
//
#include <hip/hip_runtime.h>

#define CNUM 1024
#define CDIM 256
#define TT   16
#define EPS_CAND 0.25f

// out region offsets in FP32 elements (return order: zbar, zsoft, zhard, symbols, phisoft)
#define OFF_ZBAR   ((size_t)0)
#define OFF_ZSOFT  ((size_t)16777216)
#define OFF_ZHARD  ((size_t)33554432)
#define OFF_SYM    ((size_t)50331648)
#define OFF_PHI    ((size_t)50397184)

__device__ __forceinline__ float dot4(float4 a, float4 b){
  return a.x*b.x + a.y*b.y + a.z*b.z + a.w*b.w;
}

__device__ __forceinline__ float clamp11(float v){
  return fminf(1.0f, fmaxf(-1.0f, v));
}

__device__ __forceinline__ float clamp01(float v){
  return fminf(1.0f, fmaxf(0.0f, v));
}

__global__ __launch_bounds__(512) void vq_kernel(
    const float* __restrict__ data,
    const float* __restrict__ centers,
    float* __restrict__ out)
{
  __shared__ __align__(16) float S[TT*CNUM];        // 64 KB: sq -> phisoft
  __shared__ __align__(16) float xt[TT*CDIM];       // 16 KB: x tile, then GEMM2 center tile
  __shared__ __align__(16) float sofh[2*TT*CDIM];   // 32 KB: soft fp32 | hard fp32
  __shared__ float x2s[TT];
  __shared__ int   symi[TT];

  const int tid  = threadIdx.x;
  const int lane = tid & 63;
  const int b    = blockIdx.x >> 6;          // 64 blocks per batch (1024 hw / 16)
  const int hw0  = (blockIdx.x & 63) * TT;
  const int tg   = tid >> 5;                 // token 0..15
  const int j    = tid & 31;                 // lane-in-group
  const int hbase= (lane >= 32) ? 32 : 0;    // wave-half base for shuffles

  const float* dbase = data + ((size_t)b*CDIM*1024 + hw0);

  // ---- A: stage x tile (coalesced: 16 consecutive hw per channel) ----
  #pragma unroll
  for (int i=0;i<8;i++){
    int e = tid + 512*i;            // 0..4095
    int ch = e >> 4, t = e & 15;
    xt[t*CDIM + ch] = dbase[(size_t)ch*1024 + t];
  }
  __syncthreads();

  // ---- x2 per token: 32 lanes per token, butterfly ----
  {
    float s = 0.f;
    #pragma unroll
    for (int i=0;i<8;i++){ float v = xt[tg*CDIM + j + 32*i]; s += v*v; }
    #pragma unroll
    for (int m=16;m>=1;m>>=1) s += __shfl_xor(s, m);
    if (j == 0) x2s[tg] = s;
  }
  __syncthreads();

  // ---- B: GEMM1 + inline e2 — sq[t][k] = x2 - 2 x.e + e2 ----
  {
    float acc0[TT], acc1[TT];
    #pragma unroll
    for (int t=0;t<TT;t++){ acc0[t]=0.f; acc1[t]=0.f; }
    float e20 = 0.f, e21 = 0.f;
    const float4* c0p = reinterpret_cast<const float4*>(centers) + tid*(CDIM/4);
    const float4* c1p = c0p + 512*(CDIM/4);
    for (int dc=0; dc<CDIM/4; dc+=4){
      float4 c0[4], c1[4];
      #pragma unroll
      for (int q=0;q<4;q++){ c0[q]=c0p[dc+q]; c1[q]=c1p[dc+q]; }
      #pragma unroll
      for (int q=0;q<4;q++){ e20 += dot4(c0[q],c0[q]); e21 += dot4(c1[q],c1[q]); }
      #pragma unroll
      for (int t=0;t<TT;t++){
        #pragma unroll
        for (int q=0;q<4;q++){
          float4 x4 = *reinterpret_cast<const float4*>(&xt[t*CDIM + 4*(dc+q)]);
          acc0[t] += dot4(x4, c0[q]);
          acc1[t] += dot4(x4, c1[q]);
        }
      }
    }
    #pragma unroll
    for (int t=0;t<TT;t++){
      S[t*CNUM + tid]       = x2s[t] - 2.f*acc0[t] + e20;
      S[t*CNUM + tid + 512] = x2s[t] - 2.f*acc1[t] + e21;
    }
  }
  __syncthreads();

  // ---- C1: fp32 min of sq + candidate mask (lane j owns k = j + 32*i) ----
  float a[32];
  unsigned cm = 0;
  {
    float mnsq = 3.4e38f;
    #pragma unroll
    for (int i=0;i<32;i++){
      float sq = S[tg*CNUM + j + 32*i];
      a[i] = sq;
      mnsq = fminf(mnsq, sq);
    }
    #pragma unroll
    for (int m=16;m>=1;m>>=1) mnsq = fminf(mnsq, __shfl_xor(mnsq, m));
    float thr = mnsq + EPS_CAND;
    #pragma unroll
    for (int i=0;i<32;i++) if (a[i] < thr) cm |= (1u << i);

    // ---- C2: fp64 exact refinement over candidates (~1/token expected) ----
    double bestd = 1.0e300;
    int bestk = CNUM;
    for (;;){
      unsigned long long bal = __ballot(cm != 0);
      unsigned half = (lane < 32) ? (unsigned)(bal & 0xffffffffULL)
                                  : (unsigned)(bal >> 32);
      if (!half) break;
      int src = __ffs(half) - 1;                  // local lane with pending cand
      unsigned cmsrc = (unsigned)__shfl((int)cm, hbase + src);
      int i = __ffs(cmsrc) - 1;
      int k = src + 32*i;
      if (j == src) cm &= ~(1u << i);
      // exact ||x - e_k||^2 in fp64: lane j covers dims j+32q
      double acc = 0.0;
      const float* crow = centers + (size_t)k*CDIM;
      #pragma unroll
      for (int q=0;q<8;q++){
        double xv = (double)xt[tg*CDIM + j + 32*q];
        double ev = (double)crow[j + 32*q];
        double df = xv - ev;
        acc = fma(df, df, acc);
      }
      #pragma unroll
      for (int m=16;m>=1;m>>=1) acc += __shfl_xor(acc, m);
      if (acc < bestd || (acc == bestd && k < bestk)){ bestd = acc; bestk = k; }
    }
    if (j == 0) symi[tg] = (bestk < 0) ? 0 : (bestk > 1023 ? 1023 : bestk);

    // ---- C3: stable softmax(-dist) ----
    float dmn = sqrtf(fmaxf(mnsq, 0.f));
    float sum = 0.f;
    #pragma unroll
    for (int i=0;i<32;i++){
      float d = sqrtf(fmaxf(a[i], 0.f));
      a[i] = __expf(dmn - d);
      sum += a[i];
    }
    #pragma unroll
    for (int m=16;m>=1;m>>=1) sum += __shfl_xor(sum, m);
    float rs = 1.f / sum;
    #pragma unroll
    for (int i=0;i<32;i++) S[tg*CNUM + j + 32*i] = clamp01(a[i]*rs);
  }
  __syncthreads();

  // ---- D: store phisoft (fp32, float4 along hw) + symbols (fp32) ----
  {
    #pragma unroll
    for (int it=0; it<8; it++){
      int e = tid + 512*it;          // 0..4095 = 1024 k x 4 quads
      int k = e >> 2, q = e & 3;
      float4 v;
      v.x = S[(4*q+0)*CNUM + k];
      v.y = S[(4*q+1)*CNUM + k];
      v.z = S[(4*q+2)*CNUM + k];
      v.w = S[(4*q+3)*CNUM + k];
      *reinterpret_cast<float4*>(out + OFF_PHI + ((size_t)b<<20) + ((size_t)k<<10) + hw0 + 4*q) = v;
    }
    if (tid < TT){
      out[OFF_SYM + (size_t)b*1024 + hw0 + tid] = (float)symi[tid];
    }
  }

  // ---- E: GEMM2 — softout = P @ centers, centers tiled 16 rows through LDS ----
  float4 accA = make_float4(0.f,0.f,0.f,0.f), accB = make_float4(0.f,0.f,0.f,0.f);
  {
    float4* ct = reinterpret_cast<float4*>(xt);
    const float4* cg4 = reinterpret_cast<const float4*>(centers);
    for (int kt=0; kt<CNUM/16; kt++){
      __syncthreads();
      #pragma unroll
      for (int i=0;i<2;i++){
        int f = tid + 512*i;          // 1024 float4 slots = 16 rows x 64
        ct[f] = cg4[kt*1024 + f];
      }
      __syncthreads();
      #pragma unroll
      for (int kk=0;kk<16;kk++){
        float p = S[tg*CNUM + kt*16 + kk];
        float4 cA = ct[kk*64 + j];
        float4 cB = ct[kk*64 + j + 32];
        accA.x += p*cA.x; accA.y += p*cA.y; accA.z += p*cA.z; accA.w += p*cA.w;
        accB.x += p*cB.x; accB.y += p*cB.y; accB.z += p*cB.z; accB.w += p*cB.w;
      }
    }
  }
  __syncthreads();   // all P reads done

  // ---- F: clamp soft, gather hard row, stash fp32 into sofh ----
  {
    int sy = symi[tg];
    const float4* cb = reinterpret_cast<const float4*>(centers) + sy*(CDIM/4);
    float4 h0 = cb[j], h1 = cb[j+32];
    accA.x = clamp11(accA.x); accA.y = clamp11(accA.y);
    accA.z = clamp11(accA.z); accA.w = clamp11(accA.w);
    accB.x = clamp11(accB.x); accB.y = clamp11(accB.y);
    accB.z = clamp11(accB.z); accB.w = clamp11(accB.w);
    float4* sof = reinterpret_cast<float4*>(sofh);       // [16][256] f32
    float4* hrd = sof + TT*CDIM/4;                       // [16][256] f32
    sof[tg*64 + j]      = accA;
    sof[tg*64 + j + 32] = accB;
    hrd[tg*64 + j]      = h0;
    hrd[tg*64 + j + 32] = h1;
  }
  __syncthreads();

  // ---- G: fp32 stores — zsoft from sof; zbar+zhard from hrd ----
  {
    #pragma unroll
    for (int it=0; it<2; it++){
      int e = tid + 512*it;          // 0..1023 = 256 ch x 4 quads
      int ch = e >> 2, q = e & 3;
      float4 s, h;
      s.x = sofh[(4*q+0)*CDIM + ch];
      s.y = sofh[(4*q+1)*CDIM + ch];
      s.z = sofh[(4*q+2)*CDIM + ch];
      s.w = sofh[(4*q+3)*CDIM + ch];
      h.x = sofh[TT*CDIM + (4*q+0)*CDIM + ch];
      h.y = sofh[TT*CDIM + (4*q+1)*CDIM + ch];
      h.z = sofh[TT*CDIM + (4*q+2)*CDIM + ch];
      h.w = sofh[TT*CDIM + (4*q+3)*CDIM + ch];
      size_t base = (size_t)b*262144 + (size_t)ch*1024 + hw0 + 4*q;
      *reinterpret_cast<float4*>(out + OFF_ZSOFT + base) = s;
      *reinterpret_cast<float4*>(out + OFF_ZBAR  + base) = h;
      *reinterpret_cast<float4*>(out + OFF_ZHARD + base) = h;
    }
  }
}

extern "C" void kernel_launch(void* const* d_in, const int* in_sizes, int n_in,
                              void* d_out, int out_size, void* d_ws, size_t ws_size,
                              hipStream_t stream) {
  const float* data    = (const float*)d_in[0];
  const float* centers = (const float*)d_in[1];
  float* out           = (float*)d_out;

  vq_kernel<<<dim3(4096), dim3(512), 0, stream>>>(data, centers, out);
}

// Round 7
// 556.516 us; speedup vs baseline: 4.1422x; 4.1422x over previous
//
#include <hip/hip_runtime.h>

#define CNUM 1024
#define CDIM 256
#define EPS_CAND 1.5f

// out region offsets in FP32 elements (zbar, zsoft, zhard, symbols, phisoft)
#define OFF_ZBAR   ((size_t)0)
#define OFF_ZSOFT  ((size_t)16777216)
#define OFF_ZHARD  ((size_t)33554432)
#define OFF_SYM    ((size_t)50331648)
#define OFF_PHI    ((size_t)50397184)

typedef __attribute__((ext_vector_type(8))) short bf16x8;
typedef __attribute__((ext_vector_type(4))) float f32x4;

__device__ __forceinline__ unsigned short f2bf(float f){
  unsigned u = __float_as_uint(f);
  u += 0x7fffu + ((u >> 16) & 1u);
  return (unsigned short)(u >> 16);
}
__device__ __forceinline__ float clamp11(float v){ return fminf(1.0f, fmaxf(-1.0f, v)); }
__device__ __forceinline__ float clamp01(float v){ return fminf(1.0f, fmaxf(0.0f, v)); }
__device__ __forceinline__ float dot4(float4 a, float4 b){ return a.x*b.x + a.y*b.y + a.z*b.z + a.w*b.w; }

// ---------- prep: centers fp32 -> bf16 row-major (cb16) + transposed (ct16) ----------
__global__ __launch_bounds__(256) void prep_convert(const float* __restrict__ centers,
                                                    unsigned short* __restrict__ cb16,
                                                    unsigned short* __restrict__ ct16){
  int gid = blockIdx.x*256 + threadIdx.x;        // 65536 = 1024 c x 64 quads
  int c = gid >> 6, d0 = (gid & 63)*4;
  float4 v = *reinterpret_cast<const float4*>(centers + (size_t)c*CDIM + d0);
  unsigned short b0=f2bf(v.x), b1=f2bf(v.y), b2=f2bf(v.z), b3=f2bf(v.w);
  unsigned lo = (unsigned)b0 | ((unsigned)b1<<16);
  unsigned hi = (unsigned)b2 | ((unsigned)b3<<16);
  *reinterpret_cast<uint2*>(cb16 + (size_t)c*CDIM + d0) = make_uint2(lo, hi);
  ct16[(size_t)(d0+0)*CNUM + c] = b0;
  ct16[(size_t)(d0+1)*CNUM + c] = b1;
  ct16[(size_t)(d0+2)*CNUM + c] = b2;
  ct16[(size_t)(d0+3)*CNUM + c] = b3;
}

__global__ __launch_bounds__(256) void prep_e2(const float* __restrict__ centers, float* __restrict__ e2){
  int k = blockIdx.x*256 + threadIdx.x;          // 1024
  const float4* c4 = reinterpret_cast<const float4*>(centers) + (size_t)k*(CDIM/4);
  float s = 0.f;
  #pragma unroll
  for (int i=0;i<CDIM/4;i++){ float4 v = c4[i]; s += dot4(v,v); }
  e2[k] = s;
}

// ---------- K1: GEMM1 (MFMA bf16), writes s' = e2 - 2*x.e into phisoft region ----------
// block = 64 tokens; A = centers chunk (M=16 rows), B = x^T (N=16 tokens), K = 256.
__global__ __launch_bounds__(512) void k1_gemm1(const float* __restrict__ data,
                                                const unsigned short* __restrict__ cb16,
                                                const float* __restrict__ e2g,
                                                float* __restrict__ sqo){
  __shared__ unsigned short xb[64*256];   // [t][swizzled d-slot], row=512B
  __shared__ unsigned short cb[64*256];   // [c][swizzled d-slot], 64-center chunk
  __shared__ float e2s[64];

  const int tid = threadIdx.x;
  const int w = tid>>6, lane = tid&63;
  const int l15 = lane&15, g = lane>>4;
  const int b = blockIdx.x>>4, hw0 = (blockIdx.x&15)*64;

  // stage x: wave w owns d in [32w,32w+32); lane = token
  {
    const float* dp = data + ((size_t)b*CDIM + 32*w)*1024 + hw0 + lane;
    #pragma unroll
    for (int i=0;i<16;i++){
      int dd = 2*i;
      float v0 = dp[(size_t)dd*1024];
      float v1 = dp[(size_t)(dd+1)*1024];
      unsigned pk = (unsigned)f2bf(v0) | ((unsigned)f2bf(v1)<<16);
      int d = 32*w + dd;
      int s = d>>3;
      *reinterpret_cast<unsigned*>((char*)xb + lane*512 + (((s ^ (lane&7))<<4)) + (d&7)*2) = pk;
    }
  }

  const int tt  = w & 3;     // token tile (16 tokens)
  const int ch2 = w >> 2;    // 0/1 -> centers 32*ch2 .. +32 within chunk

  for (int cc=0; cc<16; cc++){
    __syncthreads();
    // stage 64-center chunk (bf16, swizzled)
    #pragma unroll
    for (int it=0; it<4; it++){
      int e = tid + 512*it;           // 0..2047 : c = e>>5, s = e&31
      int c = e>>5, s = e&31;
      uint4 v = *reinterpret_cast<const uint4*>(cb16 + ((size_t)(cc*64 + c))*CDIM + s*8);
      *reinterpret_cast<uint4*>((char*)cb + c*512 + ((s ^ (c&7))<<4)) = v;
    }
    if (tid < 64) e2s[tid] = e2g[cc*64 + tid];
    __syncthreads();

    f32x4 acc0 = {0.f,0.f,0.f,0.f}, acc1 = {0.f,0.f,0.f,0.f};
    const int t = 16*tt + l15;
    const int c0 = 32*ch2 + l15, c1 = c0 + 16;
    #pragma unroll
    for (int k=0;k<8;k++){
      bf16x8 bf = *reinterpret_cast<const bf16x8*>((const char*)xb + t*512 + (((4*k+g) ^ (t&7))<<4));
      bf16x8 a0 = *reinterpret_cast<const bf16x8*>((const char*)cb + c0*512 + (((4*k+g) ^ (c0&7))<<4));
      bf16x8 a1 = *reinterpret_cast<const bf16x8*>((const char*)cb + c1*512 + (((4*k+g) ^ (c1&7))<<4));
      acc0 = __builtin_amdgcn_mfma_f32_16x16x32_bf16(a0, bf, acc0, 0,0,0);
      acc1 = __builtin_amdgcn_mfma_f32_16x16x32_bf16(a1, bf, acc1, 0,0,0);
    }
    // D: row = center (g*4+r within tile), col = token (l15)
    size_t outbase = (size_t)b*1048576 + (size_t)hw0 + 16*tt + l15;
    #pragma unroll
    for (int r=0;r<4;r++){
      int cr0 = 32*ch2 + 4*g + r;
      int cr1 = cr0 + 16;
      sqo[outbase + (size_t)(cc*64 + cr0)*1024] = e2s[cr0] - 2.0f*acc0[r];
      sqo[outbase + (size_t)(cc*64 + cr1)*1024] = e2s[cr1] - 2.0f*acc1[r];
    }
  }
}

// ---------- K2: softmax + exact argmin + phisoft/symbols/zbar/zhard ----------
__global__ __launch_bounds__(512) void k2_soft(const float* __restrict__ data,
                                               const float* __restrict__ centers,
                                               float* __restrict__ out){
  __shared__ float S[16*1024];
  __shared__ float x2s[16];
  __shared__ int   symi[16];

  const int tid = threadIdx.x;
  const int b = blockIdx.x>>6, hw0 = (blockIdx.x&63)*16;
  const int tg = tid>>5, j = tid&31;
  const int lane = tid&63, hbase = (lane>=32)?32:0;
  float* sqg = out + OFF_PHI;

  // stage S[t][c] from s'[c][hw]
  #pragma unroll
  for (int i=0;i<8;i++){
    int e = tid + 512*i;            // c = e>>2, q = e&3
    int c = e>>2, q = e&3;
    float4 v = *reinterpret_cast<const float4*>(sqg + (size_t)b*1048576 + (size_t)c*1024 + hw0 + 4*q);
    S[(4*q+0)*1024 + c] = v.x;
    S[(4*q+1)*1024 + c] = v.y;
    S[(4*q+2)*1024 + c] = v.z;
    S[(4*q+3)*1024 + c] = v.w;
  }
  // x2 per token from global (L1/L3-resident pattern)
  {
    float s = 0.f;
    const float* xp = data + (size_t)b*262144 + hw0 + tg;
    #pragma unroll
    for (int q=0;q<8;q++){ float v = xp[(size_t)(j+32*q)*1024]; s += v*v; }
    #pragma unroll
    for (int m=16;m>=1;m>>=1) s += __shfl_xor(s, m);
    if (j==0) x2s[tg] = s;
  }
  __syncthreads();

  // candidates + fp64 refine + softmax (sq = s' + x2)
  float a[32];
  {
    float x2 = x2s[tg];
    float mns = 3.4e38f;
    #pragma unroll
    for (int i=0;i<32;i++){ float sp = S[tg*1024 + j + 32*i]; a[i] = sp; mns = fminf(mns, sp); }
    #pragma unroll
    for (int m=16;m>=1;m>>=1) mns = fminf(mns, __shfl_xor(mns, m));
    float thr = mns + EPS_CAND;
    unsigned cm = 0;
    #pragma unroll
    for (int i=0;i<32;i++) if (a[i] < thr) cm |= (1u<<i);

    double bestd = 1.0e300; int bestk = CNUM;
    const float* xp = data + (size_t)b*262144 + hw0 + tg;
    for(;;){
      unsigned long long bal = __ballot(cm != 0);
      unsigned half = (lane<32)? (unsigned)(bal & 0xffffffffULL) : (unsigned)(bal>>32);
      if (!half) break;
      int src = __ffs(half)-1;
      unsigned cmsrc = (unsigned)__shfl((int)cm, hbase + src);
      int i = __ffs(cmsrc)-1;
      int k = src + 32*i;
      if (j==src) cm &= ~(1u<<i);
      double acc = 0.0;
      const float* crow = centers + (size_t)k*CDIM;
      #pragma unroll
      for (int q=0;q<8;q++){
        double xv = (double)xp[(size_t)(j+32*q)*1024];
        double ev = (double)crow[j+32*q];
        double df = xv-ev; acc = fma(df,df,acc);
      }
      #pragma unroll
      for (int m=16;m>=1;m>>=1) acc += __shfl_xor(acc, m);
      if (acc < bestd || (acc==bestd && k<bestk)){ bestd=acc; bestk=k; }
    }
    if (j==0) symi[tg] = (bestk<0)?0:((bestk>1023)?1023:bestk);

    float dmn = sqrtf(fmaxf(mns + x2, 0.f));
    float sum = 0.f;
    #pragma unroll
    for (int i=0;i<32;i++){
      float d = sqrtf(fmaxf(a[i] + x2, 0.f));
      a[i] = __expf(dmn - d);
      sum += a[i];
    }
    #pragma unroll
    for (int m=16;m>=1;m>>=1) sum += __shfl_xor(sum, m);
    float rs = 1.f/sum;
    #pragma unroll
    for (int i=0;i<32;i++) S[tg*1024 + j + 32*i] = clamp01(a[i]*rs);
  }
  __syncthreads();

  // phisoft stores (overwrite scratch) + symbols
  #pragma unroll
  for (int i=0;i<8;i++){
    int e = tid + 512*i;
    int k = e>>2, q = e&3;
    float4 v;
    v.x = S[(4*q+0)*1024 + k];
    v.y = S[(4*q+1)*1024 + k];
    v.z = S[(4*q+2)*1024 + k];
    v.w = S[(4*q+3)*1024 + k];
    *reinterpret_cast<float4*>(sqg + (size_t)b*1048576 + (size_t)k*1024 + hw0 + 4*q) = v;
  }
  if (tid < 16) out[OFF_SYM + (size_t)b*1024 + hw0 + tid] = (float)symi[tid];
  __syncthreads();

  // hard rows -> front of S as [16][256]
  {
    const float* crow = centers + (size_t)symi[tg]*CDIM;
    #pragma unroll
    for (int q=0;q<8;q++) S[tg*256 + j + 32*q] = crow[j+32*q];
  }
  __syncthreads();
  // zbar + zhard (transposed float4 stores along hw)
  #pragma unroll
  for (int i=0;i<2;i++){
    int e = tid + 512*i;            // 0..1023: ch = e>>2, q = e&3
    int ch = e>>2, q = e&3;
    float4 h;
    h.x = S[(4*q+0)*256 + ch];
    h.y = S[(4*q+1)*256 + ch];
    h.z = S[(4*q+2)*256 + ch];
    h.w = S[(4*q+3)*256 + ch];
    size_t base = (size_t)b*262144 + (size_t)ch*1024 + hw0 + 4*q;
    *reinterpret_cast<float4*>(out + OFF_ZBAR  + base) = h;
    *reinterpret_cast<float4*>(out + OFF_ZHARD + base) = h;
  }
}

// ---------- K3: GEMM2 (MFMA bf16): zsoft^T = centersT . phi^T ----------
// block = 64 tokens; A = centersT (M=16 dims), B = phi^T (N=16 tokens), K = 1024 centers.
__global__ __launch_bounds__(512) void k3_gemm2(const float* __restrict__ phi,
                                                const unsigned short* __restrict__ ct16,
                                                float* __restrict__ zsoft){
  __shared__ unsigned short pls[64*64];   // [t][swizzled 64-k slice], row=128B
  const int tid = threadIdx.x;
  const int w = tid>>6, lane = tid&63;
  const int l15 = lane&15, g = lane>>4;
  const int b = blockIdx.x>>4, hw0 = (blockIdx.x&15)*64;

  f32x4 acc[2][4];
  #pragma unroll
  for (int h=0;h<2;h++)
    #pragma unroll
    for (int t2=0;t2<4;t2++) acc[h][t2] = (f32x4){0.f,0.f,0.f,0.f};

  for (int ks=0; ks<16; ks++){
    int k0s = ks*64;
    __syncthreads();
    // stage phi slice transposed: [64 k][64 t] -> pls[t][swz(k)] bf16
    #pragma unroll
    for (int it=0; it<4; it++){
      int e = tid + 512*it;           // 0..2047: kp = e>>6, t = e&63
      int kp = e>>6, t = e&63;
      const float* pp = phi + (size_t)b*1048576 + (size_t)(k0s + 2*kp)*1024 + hw0 + t;
      float v0 = pp[0];
      float v1 = pp[1024];
      unsigned pk = (unsigned)f2bf(v0) | ((unsigned)f2bf(v1)<<16);
      int kk = 2*kp;
      int s = kk>>3;
      *reinterpret_cast<unsigned*>((char*)pls + t*128 + ((s ^ (t&7))<<4) + (kk&7)*2) = pk;
    }
    __syncthreads();
    #pragma unroll
    for (int ki=0; ki<2; ki++){
      int kk0 = k0s + 32*ki;
      bf16x8 a0 = *reinterpret_cast<const bf16x8*>(ct16 + (size_t)(32*w + l15)*CNUM + kk0 + 8*g);
      bf16x8 a1 = *reinterpret_cast<const bf16x8*>(ct16 + (size_t)(32*w + 16 + l15)*CNUM + kk0 + 8*g);
      #pragma unroll
      for (int t2=0;t2<4;t2++){
        int t = 16*t2 + l15;
        bf16x8 bf = *reinterpret_cast<const bf16x8*>((const char*)pls + t*128 + (((4*ki+g) ^ (t&7))<<4));
        acc[0][t2] = __builtin_amdgcn_mfma_f32_16x16x32_bf16(a0, bf, acc[0][t2], 0,0,0);
        acc[1][t2] = __builtin_amdgcn_mfma_f32_16x16x32_bf16(a1, bf, acc[1][t2], 0,0,0);
      }
    }
  }
  // D: row = dim (32w+16h+4g+r), col = token (16t2+l15)
  #pragma unroll
  for (int h=0;h<2;h++)
    #pragma unroll
    for (int t2=0;t2<4;t2++)
      #pragma unroll
      for (int r=0;r<4;r++){
        int d = 32*w + 16*h + 4*g + r;
        zsoft[(size_t)b*262144 + (size_t)d*1024 + hw0 + 16*t2 + l15] = clamp11(acc[h][t2][r]);
      }
}

extern "C" void kernel_launch(void* const* d_in, const int* in_sizes, int n_in,
                              void* d_out, int out_size, void* d_ws, size_t ws_size,
                              hipStream_t stream) {
  const float* data    = (const float*)d_in[0];
  const float* centers = (const float*)d_in[1];
  float* out           = (float*)d_out;

  unsigned short* cb16 = (unsigned short*)d_ws;                         // 512 KB
  unsigned short* ct16 = (unsigned short*)((char*)d_ws + 524288);       // 512 KB
  float*          e2   = (float*)((char*)d_ws + 1048576);               // 4 KB

  prep_convert<<<dim3(256), dim3(256), 0, stream>>>(centers, cb16, ct16);
  prep_e2<<<dim3(4), dim3(256), 0, stream>>>(centers, e2);
  k1_gemm1<<<dim3(1024), dim3(512), 0, stream>>>(data, cb16, e2, out + OFF_PHI);
  k2_soft<<<dim3(4096), dim3(512), 0, stream>>>(data, centers, out);
  k3_gemm2<<<dim3(1024), dim3(512), 0, stream>>>(out + OFF_PHI, ct16, out + OFF_ZSOFT);
}